// Round 5
// baseline (518.355 us; speedup 1.0000x reference)
//
#include <hip/hip_runtime.h>
#include <math.h>

// Problem constants
#define TC 256            // crop T
#define HC 128            // spatial H=W
#define Z2 512            // 2*T
#define Y2 256            // 2*H
#define X2 256            // 2*W
#define XS 129            // stored spectral x bins (Hermitian half)
#define XP 130            // padded x stride (float2 elems)
#define HW 16384          // HC*HC
#define LSTR256 260       // LDS line stride for 256-pt lines (float2)
#define LSTR512 519       // LDS line stride for 512-pt lines (float2)
#define MTSH 4
#define MT (1<<MTSH)      // per-thread m-tile in GEMM (16)
#define WXP 136           // Wc x-stride (float2), 136*8=1088B, 64B-aligned rows

__device__ __forceinline__ float2 cadd(float2 a, float2 b){ return make_float2(a.x+b.x, a.y+b.y); }
__device__ __forceinline__ float2 csub(float2 a, float2 b){ return make_float2(a.x-b.x, a.y-b.y); }

// w stored as e^{-2*pi*i*j/N}. SGN=-1 uses w as-is (forward), SGN=+1 uses conj(w) (inverse).
template<int SGN>
__device__ __forceinline__ float2 cmul_tw(float2 z, float2 w){
  float wy = (SGN < 0) ? w.y : -w.y;
  return make_float2(z.x*w.x - z.y*wy, z.x*wy + z.y*w.x);
}
// SGN=-1: multiply by -i ; SGN=+1: multiply by +i
template<int SGN>
__device__ __forceinline__ float2 mul_pmi(float2 t){
  return (SGN < 0) ? make_float2(t.y, -t.x) : make_float2(-t.y, t.x);
}

// In-register 16-point DFT: r[k] = sum_j r_in[j] * W16^{j*k*SGN-dir}
template<int SGN>
__device__ __forceinline__ void dft16(float2 r[16], const float2* __restrict__ tw){
  float2 u[16];
  #pragma unroll
  for (int b2=0;b2<4;b2++){
    float2 x0=r[b2], x1=r[4+b2], x2=r[8+b2], x3=r[12+b2];
    float2 t0=cadd(x0,x2), t1=csub(x0,x2), t2=cadd(x1,x3), t3=csub(x1,x3);
    float2 y0=cadd(t0,t2), y2=csub(t0,t2);
    float2 t3i = mul_pmi<SGN>(t3);
    float2 y1=cadd(t1,t3i), y3=csub(t1,t3i);
    u[0*4+b2]=y0;
    u[1*4+b2]=cmul_tw<SGN>(y1, tw[(16*b2)&255]);
    u[2*4+b2]=cmul_tw<SGN>(y2, tw[(32*b2)&255]);
    u[3*4+b2]=cmul_tw<SGN>(y3, tw[(48*b2)&255]);
  }
  #pragma unroll
  for (int e2=0;e2<4;e2++){
    float2 x0=u[e2*4+0], x1=u[e2*4+1], x2=u[e2*4+2], x3=u[e2*4+3];
    float2 t0=cadd(x0,x2), t1=csub(x0,x2), t2=cadd(x1,x3), t3=csub(x1,x3);
    float2 t3i = mul_pmi<SGN>(t3);
    r[0*4+e2]=cadd(t0,t2);
    r[1*4+e2]=cadd(t1,t3i);
    r[2*4+e2]=csub(t0,t2);
    r[3*4+e2]=csub(t1,t3i);
  }
}

// 256-pt FFT on one LDS line (contiguous 256 float2 at ln), 16 threads/line, b = lane-in-line.
template<int SGN>
__device__ __forceinline__ void fft256(float2* ln, int b, const float2* __restrict__ tw){
  float2 r[16];
  #pragma unroll
  for (int a=0;a<16;a++) r[a] = ln[16*a+b];
  dft16<SGN>(r, tw);
  #pragma unroll
  for (int e=1;e<16;e++) r[e] = cmul_tw<SGN>(r[e], tw[(b*e)&255]);
  __syncthreads();
  #pragma unroll
  for (int e=0;e<16;e++) ln[16*e+b] = r[e];
  __syncthreads();
  #pragma unroll
  for (int a=0;a<16;a++) r[a] = ln[16*b+a];
  dft16<SGN>(r, tw);
  __syncthreads();
  #pragma unroll
  for (int d=0;d<16;d++) ln[16*d+b] = r[d];
  __syncthreads();
}

// 512-pt FFT on one LDS line (contiguous 512 float2 at ln), 32 threads/line, lt in [0,32).
template<int SGN, bool CROP_OUT>
__device__ __forceinline__ void fft512(float2* ln, int lt,
        const float2* __restrict__ tw256, const float2* __restrict__ tw512){
  int team = lt >> 4, b = lt & 15;
  float2* sc = ln + team*256;
  float2 r[16];
  #pragma unroll
  for (int a=0;a<16;a++) r[a] = ln[2*(16*a+b) + team];
  dft16<SGN>(r, tw256);
  #pragma unroll
  for (int e=1;e<16;e++) r[e] = cmul_tw<SGN>(r[e], tw256[(b*e)&255]);
  __syncthreads();
  #pragma unroll
  for (int e=0;e<16;e++) sc[16*e+b] = r[e];
  __syncthreads();
  #pragma unroll
  for (int a=0;a<16;a++) r[a] = sc[16*b+a];
  dft16<SGN>(r, tw256);
  __syncthreads();
  if (team==0){
    #pragma unroll
    for (int d=0;d<16;d++) ln[16*d+b] = r[d];
  } else {
    #pragma unroll
    for (int d=0;d<16;d++){ int k=16*d+b; ln[256+k] = cmul_tw<SGN>(r[d], tw512[k]); }
  }
  __syncthreads();
  float2 res[8], res2[8];
  #pragma unroll
  for (int j=0;j<8;j++){
    int k = lt + 32*j;
    float2 E = ln[k], WO = ln[256+k];
    res[j]  = cadd(E,WO);
    res2[j] = csub(E,WO);
  }
  __syncthreads();
  #pragma unroll
  for (int j=0;j<8;j++){
    int k = lt + 32*j;
    ln[k] = res[j];
    if (!CROP_OUT) ln[256+k] = res2[j];
  }
  __syncthreads();
}

// ---------------- twiddle init ----------------
__global__ void k_init_tw(float2* tw256, float2* tw512){
  int j = threadIdx.x;  // 512 threads
  if (j < 512){
    double a = -6.283185307179586476925286766559 * (double)j / 512.0;
    tw512[j] = make_float2((float)cos(a), (float)sin(a));
  }
  if (j < 256){
    double a = -6.283185307179586476925286766559 * (double)j / 256.0;
    tw256[j] = make_float2((float)cos(a), (float)sin(a));
  }
}

// ---------------- GEMM: C[m][hw] = sum_t A[m][t]*(gz?gz[t]^4:1) * B[t][hw] ----------------
// MT=16 rows per thread, 2 hw columns per thread (float2), grid (HW/512, 256/MT).
__global__ __launch_bounds__(256) void k_gemm(const float* __restrict__ A,
    const float* __restrict__ Bv, const float* __restrict__ gz, float* __restrict__ C){
  __shared__ float As[64][MT];   // [tt][mi], scaled by zz[t]
  __shared__ float zz[256];
  int tid = threadIdx.x;
  int hw0 = blockIdx.x*512 + tid*2;
  int m0 = blockIdx.y*MT;
  float2 acc[MT];
  #pragma unroll
  for (int i=0;i<MT;i++) acc[i]=make_float2(0.f,0.f);
  {
    float s = 1.f;
    if (gz){ float g = gz[tid]; float g2=g*g; s = g2*g2; }
    zz[tid] = s;
  }
  for (int t0=0;t0<256;t0+=64){
    __syncthreads();
    #pragma unroll
    for (int e=0;e<(64*MT)/256;e++){
      int idx = e*256 + tid;
      int tt = idx >> MTSH, mi = idx & (MT-1);
      As[tt][mi] = A[(size_t)(m0+mi)*256 + t0 + tt] * zz[t0+tt];
    }
    __syncthreads();
    for (int ts=0;ts<64;ts+=8){
      float2 v[8];
      #pragma unroll
      for (int j=0;j<8;j++) v[j] = *(const float2*)(Bv + (size_t)(t0+ts+j)*HW + hw0);
      #pragma unroll
      for (int j=0;j<8;j++){
        const float4* row = (const float4*)&As[ts+j][0];
        #pragma unroll
        for (int q=0;q<MT/4;q++){
          float4 a4 = row[q];
          acc[4*q+0].x += a4.x*v[j].x; acc[4*q+0].y += a4.x*v[j].y;
          acc[4*q+1].x += a4.y*v[j].x; acc[4*q+1].y += a4.y*v[j].y;
          acc[4*q+2].x += a4.z*v[j].x; acc[4*q+2].y += a4.z*v[j].y;
          acc[4*q+3].x += a4.w*v[j].x; acc[4*q+3].y += a4.w*v[j].y;
        }
      }
    }
  }
  #pragma unroll
  for (int mi=0;mi<MT;mi++) *(float2*)(C + (size_t)(m0+mi)*HW + hw0) = acc[mi];
}

// ---------------- Pass 1: R2C along x (zero-pad 128->256), lines (m<256, y<128) ----------------
__global__ __launch_bounds__(256) void k_fft_x_fwd(const float* __restrict__ tmp,
     float2* __restrict__ S, const float2* __restrict__ tw256){
  __shared__ float2 buf[16*LSTR256];
  int tid = threadIdx.x;
  int w = tid >> 4, b = tid & 15;
  int line = blockIdx.x*16 + w;       // 32768 lines
  int m = line >> 7, y = line & 127;
  float2* ln = buf + w*LSTR256;
  const float* src = tmp + (size_t)(m*128 + y)*128;
  #pragma unroll
  for (int a=0;a<16;a++){
    int n = 16*a + b;
    ln[n] = make_float2((n<128)? src[n] : 0.f, 0.f);
  }
  __syncthreads();
  fft256<-1>(ln, b, tw256);
  float2* dst = S + ((size_t)m*256 + y)*XP;
  #pragma unroll
  for (int a=0;a<8;a++){
    int k = 16*a + b;
    dst[k] = ln[k];
  }
  if (b==0) dst[128] = ln[128];
}

// ---------------- Pass 2: fwd along y (z<256), input y<128 nonzero, x<129 ----------------
__global__ __launch_bounds__(256) void k_fft_y_fwd(float2* __restrict__ S, const float2* __restrict__ tw256){
  __shared__ float2 buf[16*LSTR256];
  int tid = threadIdx.x;
  int w = tid & 15, b = tid >> 4;
  int z = blockIdx.x;               // 0..255
  int x = blockIdx.y*16 + w;        // up to 143
  bool act = (x < XS);
  float2* ln = buf + w*LSTR256;
  size_t base = ((size_t)z*256)*XP + x;
  #pragma unroll
  for (int a=0;a<8;a++){
    int n = 16*a + b;   // y 0..127
    ln[n] = act ? S[base + (size_t)n*XP] : make_float2(0.f,0.f);
    ln[n+128] = make_float2(0.f,0.f);
  }
  __syncthreads();
  fft256<-1>(ln, b, tw256);
  #pragma unroll
  for (int a=0;a<16;a++){
    int n = 16*a + b;
    if (act) S[base + (size_t)n*XP] = ln[n];
  }
}

// ---------------- Filter precompute: Wc[ly][n][x] = (R + (w0+w0m)/2) + i(I + (w1-w1m)/2), *1/N --
// One 64-thread block per (n, ly) row; forward reads ascending-contiguous, mirror reads
// descending-contiguous, output row contiguous (stride WXP=136 -> 64B aligned).
__global__ __launch_bounds__(64) void k_prep_w(const float* __restrict__ R,
    const float* __restrict__ I, const float* __restrict__ w0, const float* __restrict__ w1,
    float2* __restrict__ Wc, int y0){
  const float sc = 1.f/33554432.f;   // 1/(512*256*256)
  int n  = blockIdx.x;        // kz 0..511
  int ly = blockIdx.y;        // 0..127
  int y  = y0 + ly;
  int t  = threadIdx.x;       // 0..63
  unsigned mz = (512u - (unsigned)n) & 511u;
  unsigned my = (256u - (unsigned)y) & 255u;
  size_t fb = (size_t)n*65536 + (size_t)y*256;
  size_t mb = (size_t)mz*65536 + (size_t)my*256;
  float2* orow = Wc + ((size_t)ly*512 + n)*WXP;
  int x0 = 2*t;
  float2 R2  = *(const float2*)(R  + fb + x0);
  float2 I2  = *(const float2*)(I  + fb + x0);
  float2 w02 = *(const float2*)(w0 + fb + x0);
  float2 w12 = *(const float2*)(w1 + fb + x0);
  float w0m0 = w0[mb + ((256 - x0) & 255)];
  float w0m1 = w0[mb + (255 - x0)];
  float w1m0 = w1[mb + ((256 - x0) & 255)];
  float w1m1 = w1[mb + (255 - x0)];
  float4 o;
  o.x = (R2.x + 0.5f*(w02.x + w0m0))*sc;
  o.y = (I2.x + 0.5f*(w12.x - w1m0))*sc;
  o.z = (R2.y + 0.5f*(w02.y + w0m1))*sc;
  o.w = (I2.y + 0.5f*(w12.y - w1m1))*sc;
  *(float4*)(orow + x0) = o;
  if (t == 0){
    float wr = (R[fb+128] + 0.5f*(w0[fb+128] + w0[mb+128]))*sc;
    float wi = (I[fb+128] + 0.5f*(w1[fb+128] - w1[mb+128]))*sc;
    orow[128] = make_float2(wr, wi);
  }
}

// ---------------- Fused z pass: fwd 512-FFT + precomputed filter + inv 512-FFT, keep z<256 -----
// Processes y in [y0, y0+128). Wc is the half-volume filter for this y-range.
// Lanes 0-7 = consecutive x -> Wc reads are 8 fully-used 64B lines per wave-load.
__global__ __launch_bounds__(256) void k_fft_z_filt(float2* __restrict__ S,
      const float2* __restrict__ Wc, int y0,
      const float2* __restrict__ tw256, const float2* __restrict__ tw512){
  __shared__ float2 buf[8*LSTR512];
  int tid = threadIdx.x;
  int w = tid & 7, lt = tid >> 3;
  int ly = blockIdx.y;              // 0..127
  int y  = y0 + ly;
  int x  = blockIdx.x*8 + w;        // up to 135
  bool act = (x < XS);
  float2* ln = buf + w*LSTR512;
  size_t base = (size_t)y*XP + x;
  #pragma unroll
  for (int a=0;a<16;a++){
    int n = 32*a + lt;
    ln[n] = (act && n<256) ? S[base + (size_t)n*256*XP] : make_float2(0.f,0.f);
  }
  __syncthreads();
  fft512<-1,false>(ln, lt, tw256, tw512);
  if (act){
    const float2* wrow = Wc + (size_t)ly*512*WXP + x;
    #pragma unroll
    for (int a=0;a<16;a++){
      int n = 32*a + lt;
      float2 W = wrow[(size_t)n*WXP];
      float2 v = ln[n];
      ln[n] = make_float2(v.x*W.x - v.y*W.y, v.x*W.y + v.y*W.x);
    }
  }
  __syncthreads();
  fft512<1,true>(ln, lt, tw256, tw512);
  #pragma unroll
  for (int a=0;a<8;a++){
    int n = 32*a + lt;   // 0..255
    if (act) S[base + (size_t)n*256*XP] = ln[n];
  }
}

// ---------------- Pass 6: inv along y (z<256), keep y<128 ----------------
__global__ __launch_bounds__(256) void k_fft_y_inv(float2* __restrict__ S, const float2* __restrict__ tw256){
  __shared__ float2 buf[16*LSTR256];
  int tid = threadIdx.x;
  int w = tid & 15, b = tid >> 4;
  int z = blockIdx.x;       // t 0..255
  int x = blockIdx.y*16 + w;
  bool act = (x < XS);
  float2* ln = buf + w*LSTR256;
  size_t base = ((size_t)z*256)*XP + x;
  #pragma unroll
  for (int a=0;a<16;a++){
    int n = 16*a + b;
    ln[n] = act ? S[base + (size_t)n*XP] : make_float2(0.f,0.f);
  }
  __syncthreads();
  fft256<1>(ln, b, tw256);
  #pragma unroll
  for (int a=0;a<8;a++){
    int n = 16*a + b;    // 0..127
    if (act) S[base + (size_t)n*XP] = ln[n];
  }
}

// ---------------- Pass 7: inv C2R along x, keep x<128, write real vol ----------------
__global__ __launch_bounds__(256) void k_fft_x_inv(const float2* __restrict__ S,
      float* __restrict__ vol, const float2* __restrict__ tw256){
  __shared__ float2 buf[16*LSTR256];
  int tid = threadIdx.x;
  int w = tid >> 4, b = tid & 15;
  int line = blockIdx.x*16 + w;   // t*128 + y
  int t = line >> 7, y = line & 127;
  float2* ln = buf + w*LSTR256;
  const float2* src = S + ((size_t)t*256 + y)*XP;
  #pragma unroll
  for (int a=0;a<8;a++){
    int k = 16*a + b;
    ln[k] = src[k];
  }
  if (b==0) ln[128] = src[128];
  __syncthreads();
  #pragma unroll
  for (int a=8;a<16;a++){
    int k = 16*a + b;     // 128..255
    if (k > 128){ float2 v = ln[256-k]; ln[k] = make_float2(v.x, -v.y); }
  }
  __syncthreads();
  fft256<1>(ln, b, tw256);
  float* dst = vol + (size_t)(t*128 + y)*128;
  #pragma unroll
  for (int a=0;a<8;a++){
    int n = 16*a + b;
    dst[n] = ln[n].x;
  }
}

extern "C" void kernel_launch(void* const* d_in, const int* in_sizes, int n_in,
                              void* d_out, int out_size, void* d_ws, size_t ws_size,
                              hipStream_t stream) {
  const float* fet = (const float*)d_in[0];           // (1,1,256,128,128)
  const float* gz  = (const float*)d_in[1];           // (1,256,1,1)
  const float* mtx = (const float*)d_in[2];           // (256,256)
  const float* mtxi= (const float*)d_in[3];           // (256,256)
  const float* Rr  = (const float*)d_in[4];           // (512,256,256)
  const float* Ii  = (const float*)d_in[5];           // (512,256,256)
  const float* lw  = (const float*)d_in[6];           // (2,512,256,256)
  const float* w0  = lw;
  const float* w1  = lw + (size_t)Z2*Y2*X2;
  float* out = (float*)d_out;

  char* ws = (char*)d_ws;
  const size_t OFF_TW256 = 0;
  const size_t OFF_TW512 = 2048;
  const size_t OFF_S     = 8192;
  const size_t S_BYTES   = (size_t)256*256*XP*sizeof(float2);        // 68.2 MB (z<256 only)
  const size_t OFF_SCR   = OFF_S + S_BYTES;                          // shared scratch region:
  const size_t WC_BYTES  = (size_t)128*512*WXP*sizeof(float2);       // 71.3 MB (half-volume W)
  const size_t TMP_BYTES = (size_t)TC*HW*sizeof(float);              // 16.8 MB
  const size_t SCR_BYTES = (WC_BYTES > TMP_BYTES ? WC_BYTES : TMP_BYTES);
  const size_t NEED      = OFF_SCR + SCR_BYTES;                      // ~139.5 MB
  if (ws_size < NEED) return;   // diagnostic: leaves d_out zero

  float2* tw256 = (float2*)(ws + OFF_TW256);
  float2* tw512 = (float2*)(ws + OFF_TW512);
  float2* S     = (float2*)(ws + OFF_S);
  float*  tmp   = (float*)(ws + OFF_SCR);   // live: gemm -> x_fwd
  float2* Wc    = (float2*)(ws + OFF_SCR);  // live: prep_w -> z_filt (per half)
  float*  vol   = (float*)(ws + OFF_SCR);   // live: x_inv -> gemm2

  hipLaunchKernelGGL(k_init_tw, dim3(1), dim3(512), 0, stream, tw256, tw512);
  hipLaunchKernelGGL(k_gemm, dim3(32,256/MT), dim3(256), 0, stream, mtx, fet, gz, tmp);
  hipLaunchKernelGGL(k_fft_x_fwd, dim3(2048), dim3(256), 0, stream, tmp, S, tw256);
  hipLaunchKernelGGL(k_fft_y_fwd, dim3(256,9), dim3(256), 0, stream, S, tw256);
  hipLaunchKernelGGL(k_prep_w, dim3(512,128), dim3(64), 0, stream, Rr, Ii, w0, w1, Wc, 0);
  hipLaunchKernelGGL(k_fft_z_filt, dim3(17,128), dim3(256), 0, stream, S, Wc, 0, tw256, tw512);
  hipLaunchKernelGGL(k_prep_w, dim3(512,128), dim3(64), 0, stream, Rr, Ii, w0, w1, Wc, 128);
  hipLaunchKernelGGL(k_fft_z_filt, dim3(17,128), dim3(256), 0, stream, S, Wc, 128, tw256, tw512);
  hipLaunchKernelGGL(k_fft_y_inv, dim3(256,9), dim3(256), 0, stream, S, tw256);
  hipLaunchKernelGGL(k_fft_x_inv, dim3(2048), dim3(256), 0, stream, S, vol, tw256);
  hipLaunchKernelGGL(k_gemm, dim3(32,256/MT), dim3(256), 0, stream, mtxi, vol, (const float*)nullptr, out);
}

// Round 6
// 308.277 us; speedup vs baseline: 1.6815x; 1.6815x over previous
//
#include <hip/hip_runtime.h>
#include <math.h>

// Problem constants
#define TC 256            // crop T
#define HC 128            // spatial H=W
#define Z2 512            // 2*T
#define Y2 256            // 2*H
#define X2 256            // 2*W
#define HW 16384          // HC*HC
#define LSTR256 260       // LDS line stride for 256-pt lines (float2)
#define LSTR512 519       // LDS line stride for 512-pt lines (float2)
#define MTSH 4
#define MT (1<<MTSH)      // per-thread m-tile in GEMM (16)
#define WPAD 132          // row stride (float2) for A/B spectral arrays (1056B, non-pow2)
#define KZS 257           // stored z-spectral bins (Hermitian half along z)

__device__ __forceinline__ float2 cadd(float2 a, float2 b){ return make_float2(a.x+b.x, a.y+b.y); }
__device__ __forceinline__ float2 csub(float2 a, float2 b){ return make_float2(a.x-b.x, a.y-b.y); }

// w stored as e^{-2*pi*i*j/N}. SGN=-1 uses w as-is (forward), SGN=+1 uses conj(w) (inverse).
template<int SGN>
__device__ __forceinline__ float2 cmul_tw(float2 z, float2 w){
  float wy = (SGN < 0) ? w.y : -w.y;
  return make_float2(z.x*w.x - z.y*wy, z.x*wy + z.y*w.x);
}
// SGN=-1: multiply by -i ; SGN=+1: multiply by +i
template<int SGN>
__device__ __forceinline__ float2 mul_pmi(float2 t){
  return (SGN < 0) ? make_float2(t.y, -t.x) : make_float2(-t.y, t.x);
}

// In-register 16-point DFT
template<int SGN>
__device__ __forceinline__ void dft16(float2 r[16], const float2* __restrict__ tw){
  float2 u[16];
  #pragma unroll
  for (int b2=0;b2<4;b2++){
    float2 x0=r[b2], x1=r[4+b2], x2=r[8+b2], x3=r[12+b2];
    float2 t0=cadd(x0,x2), t1=csub(x0,x2), t2=cadd(x1,x3), t3=csub(x1,x3);
    float2 y0=cadd(t0,t2), y2=csub(t0,t2);
    float2 t3i = mul_pmi<SGN>(t3);
    float2 y1=cadd(t1,t3i), y3=csub(t1,t3i);
    u[0*4+b2]=y0;
    u[1*4+b2]=cmul_tw<SGN>(y1, tw[(16*b2)&255]);
    u[2*4+b2]=cmul_tw<SGN>(y2, tw[(32*b2)&255]);
    u[3*4+b2]=cmul_tw<SGN>(y3, tw[(48*b2)&255]);
  }
  #pragma unroll
  for (int e2=0;e2<4;e2++){
    float2 x0=u[e2*4+0], x1=u[e2*4+1], x2=u[e2*4+2], x3=u[e2*4+3];
    float2 t0=cadd(x0,x2), t1=csub(x0,x2), t2=cadd(x1,x3), t3=csub(x1,x3);
    float2 t3i = mul_pmi<SGN>(t3);
    r[0*4+e2]=cadd(t0,t2);
    r[1*4+e2]=cadd(t1,t3i);
    r[2*4+e2]=csub(t0,t2);
    r[3*4+e2]=csub(t1,t3i);
  }
}

// 256-pt FFT on one LDS line (contiguous 256 float2 at ln), 16 threads/line, b = lane-in-line.
// Caller must __syncthreads() after filling ln.
template<int SGN>
__device__ __forceinline__ void fft256(float2* ln, int b, const float2* __restrict__ tw){
  float2 r[16];
  #pragma unroll
  for (int a=0;a<16;a++) r[a] = ln[16*a+b];
  dft16<SGN>(r, tw);
  #pragma unroll
  for (int e=1;e<16;e++) r[e] = cmul_tw<SGN>(r[e], tw[(b*e)&255]);
  __syncthreads();
  #pragma unroll
  for (int e=0;e<16;e++) ln[16*e+b] = r[e];
  __syncthreads();
  #pragma unroll
  for (int a=0;a<16;a++) r[a] = ln[16*b+a];
  dft16<SGN>(r, tw);
  __syncthreads();
  #pragma unroll
  for (int d=0;d<16;d++) ln[16*d+b] = r[d];
  __syncthreads();
}

// 512-pt FFT on one LDS line (contiguous 512 float2 at ln), 32 threads/line, lt in [0,32).
template<int SGN, bool CROP_OUT>
__device__ __forceinline__ void fft512(float2* ln, int lt,
        const float2* __restrict__ tw256, const float2* __restrict__ tw512){
  int team = lt >> 4, b = lt & 15;
  float2* sc = ln + team*256;
  float2 r[16];
  #pragma unroll
  for (int a=0;a<16;a++) r[a] = ln[2*(16*a+b) + team];
  dft16<SGN>(r, tw256);
  #pragma unroll
  for (int e=1;e<16;e++) r[e] = cmul_tw<SGN>(r[e], tw256[(b*e)&255]);
  __syncthreads();
  #pragma unroll
  for (int e=0;e<16;e++) sc[16*e+b] = r[e];
  __syncthreads();
  #pragma unroll
  for (int a=0;a<16;a++) r[a] = sc[16*b+a];
  dft16<SGN>(r, tw256);
  __syncthreads();
  if (team==0){
    #pragma unroll
    for (int d=0;d<16;d++) ln[16*d+b] = r[d];
  } else {
    #pragma unroll
    for (int d=0;d<16;d++){ int k=16*d+b; ln[256+k] = cmul_tw<SGN>(r[d], tw512[k]); }
  }
  __syncthreads();
  float2 res[8], res2[8];
  #pragma unroll
  for (int j=0;j<8;j++){
    int k = lt + 32*j;
    float2 E = ln[k], WO = ln[256+k];
    res[j]  = cadd(E,WO);
    res2[j] = csub(E,WO);
  }
  __syncthreads();
  #pragma unroll
  for (int j=0;j<8;j++){
    int k = lt + 32*j;
    ln[k] = res[j];
    if (!CROP_OUT) ln[256+k] = res2[j];
  }
  __syncthreads();
}

// ---------------- twiddle init ----------------
__global__ void k_init_tw(float2* tw256, float2* tw512){
  int j = threadIdx.x;  // 512 threads
  if (j < 512){
    double a = -6.283185307179586476925286766559 * (double)j / 512.0;
    tw512[j] = make_float2((float)cos(a), (float)sin(a));
  }
  if (j < 256){
    double a = -6.283185307179586476925286766559 * (double)j / 256.0;
    tw256[j] = make_float2((float)cos(a), (float)sin(a));
  }
}

// ---------------- GEMM: C[m][hw] = sum_t A[m][t]*(gz?gz[t]^4:1) * B[t][hw] ----------------
__global__ __launch_bounds__(256) void k_gemm(const float* __restrict__ A,
    const float* __restrict__ Bv, const float* __restrict__ gz, float* __restrict__ C){
  __shared__ float As[64][MT];   // [tt][mi], scaled by zz[t]
  __shared__ float zz[256];
  int tid = threadIdx.x;
  int hw0 = blockIdx.x*512 + tid*2;
  int m0 = blockIdx.y*MT;
  float2 acc[MT];
  #pragma unroll
  for (int i=0;i<MT;i++) acc[i]=make_float2(0.f,0.f);
  {
    float s = 1.f;
    if (gz){ float g = gz[tid]; float g2=g*g; s = g2*g2; }
    zz[tid] = s;
  }
  for (int t0=0;t0<256;t0+=64){
    __syncthreads();
    #pragma unroll
    for (int e=0;e<(64*MT)/256;e++){
      int idx = e*256 + tid;
      int tt = idx >> MTSH, mi = idx & (MT-1);
      As[tt][mi] = A[(size_t)(m0+mi)*256 + t0 + tt] * zz[t0+tt];
    }
    __syncthreads();
    for (int ts=0;ts<64;ts+=8){
      float2 v[8];
      #pragma unroll
      for (int j=0;j<8;j++) v[j] = *(const float2*)(Bv + (size_t)(t0+ts+j)*HW + hw0);
      #pragma unroll
      for (int j=0;j<8;j++){
        const float4* row = (const float4*)&As[ts+j][0];
        #pragma unroll
        for (int q=0;q<MT/4;q++){
          float4 a4 = row[q];
          acc[4*q+0].x += a4.x*v[j].x; acc[4*q+0].y += a4.x*v[j].y;
          acc[4*q+1].x += a4.y*v[j].x; acc[4*q+1].y += a4.y*v[j].y;
          acc[4*q+2].x += a4.z*v[j].x; acc[4*q+2].y += a4.z*v[j].y;
          acc[4*q+3].x += a4.w*v[j].x; acc[4*q+3].y += a4.w*v[j].y;
        }
      }
    }
  }
  #pragma unroll
  for (int mi=0;mi<MT;mi++) *(float2*)(C + (size_t)(m0+mi)*HW + hw0) = acc[mi];
}

// ---------------- Pass 1: fwd 512-pt z-FFT of real tmp, keep kz<=256 -> A[kz][h][wx] ----------
__global__ __launch_bounds__(256) void k_fft_zf(const float* __restrict__ tmp,
      float2* __restrict__ A, const float2* __restrict__ tw256, const float2* __restrict__ tw512){
  __shared__ float2 buf[8*LSTR512];
  int tid = threadIdx.x;
  int w = tid & 7, lt = tid >> 3;
  int hw = blockIdx.x*8 + w;           // 0..16383
  int h = hw >> 7, wx = hw & 127;
  float2* ln = buf + w*LSTR512;
  #pragma unroll
  for (int a=0;a<16;a++){
    int n = 32*a + lt;
    ln[n] = (n<256) ? make_float2(tmp[(size_t)n*HW + hw], 0.f) : make_float2(0.f,0.f);
  }
  __syncthreads();
  fft512<-1,false>(ln, lt, tw256, tw512);
  size_t colbase = (size_t)h*WPAD + wx;
  #pragma unroll
  for (int a=0;a<8;a++){
    int n = 32*a + lt;
    A[(size_t)n*(128*WPAD) + colbase] = ln[n];
  }
  if (lt==0) A[(size_t)256*(128*WPAD) + colbase] = ln[256];
}

// ---------------- Pass 2: fwd y-FFT (128 -> 256) : A[kz][h][wx] -> B[kz][ky][wx] --------------
__global__ __launch_bounds__(256) void k_fft_yf(const float2* __restrict__ A,
      float2* __restrict__ B, const float2* __restrict__ tw256){
  __shared__ float2 buf[16*LSTR256];
  int tid = threadIdx.x;
  int w = tid & 15, b = tid >> 4;
  int kz = blockIdx.x;                 // 0..256
  int wx = blockIdx.y*16 + w;          // 0..127
  float2* ln = buf + w*LSTR256;
  size_t abase = (size_t)kz*(128*WPAD) + wx;
  #pragma unroll
  for (int a=0;a<8;a++){
    int n = 16*a + b;   // h 0..127
    ln[n] = A[abase + (size_t)n*WPAD];
    ln[n+128] = make_float2(0.f,0.f);
  }
  __syncthreads();
  fft256<-1>(ln, b, tw256);
  size_t bbase = (size_t)kz*(256*WPAD) + wx;
  #pragma unroll
  for (int a=0;a<16;a++){
    int n = 16*a + b;
    B[bbase + (size_t)n*WPAD] = ln[n];
  }
}

// ---------------- Pass 3: fused x-FFT (zero-pad 128->256) + filter + inv x-FFT, keep x<128 ----
// One (kz,ky) row per 16 threads; 16 rows/block. Table rows are contiguous 1KB reads
// (forward ascending, mirror descending), each element read exactly once.
__global__ __launch_bounds__(256) void k_x_filt(float2* __restrict__ B,
      const float* __restrict__ R, const float* __restrict__ I,
      const float* __restrict__ w0, const float* __restrict__ w1,
      const float2* __restrict__ tw256){
  __shared__ float2 buf[16*LSTR256];
  const float sc = 1.f/33554432.f;     // 1/(512*256*256)
  int tid = threadIdx.x;
  int wl = tid >> 4, b = tid & 15;
  int kz = blockIdx.y;                 // 0..256
  int ky = blockIdx.x*16 + wl;         // 0..255
  float2* ln = buf + wl*LSTR256;
  size_t rb = ((size_t)kz*256 + ky)*WPAD;
  #pragma unroll
  for (int a=0;a<8;a++){
    int n = 16*a + b;
    ln[n] = B[rb + n];
    ln[n+128] = make_float2(0.f,0.f);
  }
  __syncthreads();
  fft256<-1>(ln, b, tw256);
  unsigned mz = (512u - (unsigned)kz) & 511u;
  unsigned my = (256u - (unsigned)ky) & 255u;
  size_t trow = ((size_t)kz<<16) + (size_t)ky*256;
  size_t mrow = ((size_t)mz<<16) + (size_t)my*256;
  #pragma unroll
  for (int a=0;a<16;a++){
    int kx = 16*a + b;
    int mx = (256 - kx) & 255;
    float wr = (R[trow+kx] + 0.5f*(w0[trow+kx] + w0[mrow+mx]))*sc;
    float wi = (I[trow+kx] + 0.5f*(w1[trow+kx] - w1[mrow+mx]))*sc;
    float2 v = ln[kx];
    ln[kx] = make_float2(v.x*wr - v.y*wi, v.x*wi + v.y*wr);
  }
  // no sync needed: each thread rewrote exactly the ln elements (16a+b) that it
  // itself reads first inside fft256; cross-thread reads occur after its internal sync
  fft256<1>(ln, b, tw256);
  #pragma unroll
  for (int a=0;a<8;a++){
    int n = 16*a + b;    // x 0..127
    B[rb + n] = ln[n];
  }
}

// ---------------- Pass 4: inv y-FFT, keep y<128 : B[kz][ky][wx] -> A[kz][h][wx] ---------------
__global__ __launch_bounds__(256) void k_fft_yi(const float2* __restrict__ B,
      float2* __restrict__ A, const float2* __restrict__ tw256){
  __shared__ float2 buf[16*LSTR256];
  int tid = threadIdx.x;
  int w = tid & 15, b = tid >> 4;
  int kz = blockIdx.x;                 // 0..256
  int wx = blockIdx.y*16 + w;          // 0..127
  float2* ln = buf + w*LSTR256;
  size_t bbase = (size_t)kz*(256*WPAD) + wx;
  #pragma unroll
  for (int a=0;a<16;a++){
    int n = 16*a + b;
    ln[n] = B[bbase + (size_t)n*WPAD];
  }
  __syncthreads();
  fft256<1>(ln, b, tw256);
  size_t abase = (size_t)kz*(128*WPAD) + wx;
  #pragma unroll
  for (int a=0;a<8;a++){
    int n = 16*a + b;    // h 0..127
    A[abase + (size_t)n*WPAD] = ln[n];
  }
}

// ---------------- Pass 5: inv 512-pt z-FFT with Hermitian reconstruction, write real t<256 ----
__global__ __launch_bounds__(256) void k_fft_zi(const float2* __restrict__ A,
      float* __restrict__ vol, const float2* __restrict__ tw256, const float2* __restrict__ tw512){
  __shared__ float2 buf[8*LSTR512];
  int tid = threadIdx.x;
  int w = tid & 7, lt = tid >> 3;
  int hw = blockIdx.x*8 + w;
  int h = hw >> 7, wx = hw & 127;
  float2* ln = buf + w*LSTR512;
  size_t colbase = (size_t)h*WPAD + wx;
  #pragma unroll
  for (int a=0;a<8;a++){
    int n = 32*a + lt;
    ln[n] = A[(size_t)n*(128*WPAD) + colbase];
  }
  if (lt==0) ln[256] = A[(size_t)256*(128*WPAD) + colbase];
  __syncthreads();
  #pragma unroll
  for (int a=8;a<16;a++){
    int n = 32*a + lt;   // 256..511
    if (n > 256){ float2 v = ln[512-n]; ln[n] = make_float2(v.x, -v.y); }
  }
  __syncthreads();
  fft512<1,true>(ln, lt, tw256, tw512);
  #pragma unroll
  for (int a=0;a<8;a++){
    int n = 32*a + lt;   // t 0..255
    vol[(size_t)n*HW + hw] = ln[n].x;
  }
}

extern "C" void kernel_launch(void* const* d_in, const int* in_sizes, int n_in,
                              void* d_out, int out_size, void* d_ws, size_t ws_size,
                              hipStream_t stream) {
  const float* fet = (const float*)d_in[0];           // (1,1,256,128,128)
  const float* gz  = (const float*)d_in[1];           // (1,256,1,1)
  const float* mtx = (const float*)d_in[2];           // (256,256)
  const float* mtxi= (const float*)d_in[3];           // (256,256)
  const float* Rr  = (const float*)d_in[4];           // (512,256,256)
  const float* Ii  = (const float*)d_in[5];           // (512,256,256)
  const float* lw  = (const float*)d_in[6];           // (2,512,256,256)
  const float* w0  = lw;
  const float* w1  = lw + (size_t)Z2*Y2*X2;
  float* out = (float*)d_out;

  char* ws = (char*)d_ws;
  const size_t OFF_TW256 = 0;
  const size_t OFF_TW512 = 2048;
  const size_t OFF_TMP   = 8192;                                      // tmp / vol (17 MB)
  const size_t TMP_BYTES = (size_t)TC*HW*sizeof(float);
  const size_t OFF_A     = OFF_TMP + TMP_BYTES;
  const size_t A_BYTES   = (size_t)KZS*128*WPAD*sizeof(float2);       // 34.7 MB
  const size_t OFF_B     = OFF_A + A_BYTES;
  const size_t B_BYTES   = (size_t)KZS*256*WPAD*sizeof(float2);       // 69.5 MB
  const size_t NEED      = OFF_B + B_BYTES;                           // ~121 MB
  if (ws_size < NEED) return;   // diagnostic: leaves d_out zero

  float2* tw256 = (float2*)(ws + OFF_TW256);
  float2* tw512 = (float2*)(ws + OFF_TW512);
  float*  tmp   = (float*)(ws + OFF_TMP);   // live: gemm -> zf
  float*  vol   = (float*)(ws + OFF_TMP);   // live: zi -> gemm2
  float2* A     = (float2*)(ws + OFF_A);
  float2* B     = (float2*)(ws + OFF_B);

  hipLaunchKernelGGL(k_init_tw, dim3(1), dim3(512), 0, stream, tw256, tw512);
  hipLaunchKernelGGL(k_gemm, dim3(32,256/MT), dim3(256), 0, stream, mtx, fet, gz, tmp);
  hipLaunchKernelGGL(k_fft_zf, dim3(2048), dim3(256), 0, stream, tmp, A, tw256, tw512);
  hipLaunchKernelGGL(k_fft_yf, dim3(KZS,8), dim3(256), 0, stream, A, B, tw256);
  hipLaunchKernelGGL(k_x_filt, dim3(16,KZS), dim3(256), 0, stream, B, Rr, Ii, w0, w1, tw256);
  hipLaunchKernelGGL(k_fft_yi, dim3(KZS,8), dim3(256), 0, stream, B, A, tw256);
  hipLaunchKernelGGL(k_fft_zi, dim3(2048), dim3(256), 0, stream, A, vol, tw256, tw512);
  hipLaunchKernelGGL(k_gemm, dim3(32,256/MT), dim3(256), 0, stream, mtxi, vol, (const float*)nullptr, out);
}